// Round 3
// baseline (229.812 us; speedup 1.0000x reference)
//
#include <hip/hip_runtime.h>

// SpikeFP32LayerNorm: LayerNorm (no affine) over rows of (8192, 4096) fp32,
// statistics + normalization in FP64 per the reference circuit:
//   mean = sum(x64)/N ; c = x64 - mean ; var = sum(c*c)/N ; vpe = var + 1e-6
//   y = 1/vpe ; 5x NR: y = 0.5*y*(3 - vpe*y*y) ; out = fp32(c * y)
//
// v4: v3 structure, NONTEMPORAL HINTS REMOVED (single-variable A/B).
//   v1/v2/v3 (all NT) converge to 57.5-62 us kernel time (~4.7 TB/s) despite
//   large schedule differences -> limiter is a common constant factor.
//   Suspect: nt loads/stores bypass L2, so HBM sees small unstaged bursts;
//   the plain-copy regime (m13, 6.29 TB/s) and the harness fills (6.75 TB/s,
//   plain stores) both go through L2. This version uses plain cached
//   vec4 loads/stores; everything else is bit-identical to v3.
// Accumulation order identical to v2/v3 (bit-exact, absmax 0.0).

#define LN_BATCH   8192
#define LN_N       4096
#define LN_THREADS 256            // 4 waves, one row at a time per block
#define LN_WAVES   4
#define LN_F4PT    4              // vec4 per lane: 16 elems/lane
#define LN_GRID    2048           // persistent blocks
#define LN_ROWS_PB (LN_BATCH / LN_GRID)   // 4 rows per block
#define LN_EPS     1e-6

typedef float vfloat4 __attribute__((ext_vector_type(4)));

__device__ __forceinline__ double wave_allreduce_add(double s) {
#pragma unroll
    for (int off = 1; off < 64; off <<= 1)
        s += __shfl_xor(s, off, 64);
    return s;
}

__global__ __launch_bounds__(LN_THREADS, 7)
void spike_layernorm_kernel(const float* __restrict__ x, float* __restrict__ out) {
    const int wave = threadIdx.x >> 6;
    const int lane = threadIdx.x & 63;
    // vec4 index within the row: each wave owns a contiguous quarter (256 vec4)
    const int vbase = wave * (LN_N / 4 / LN_WAVES) + lane;

    __shared__ double red[2][LN_WAVES];

    // Prologue: load row blockIdx.x (plain cached loads)
    vfloat4 v[LN_F4PT];
    {
        const vfloat4* __restrict__ xr =
            reinterpret_cast<const vfloat4*>(x + (size_t)blockIdx.x * LN_N);
#pragma unroll
        for (int i = 0; i < LN_F4PT; ++i)
            v[i] = xr[vbase + i * 64];
    }

#pragma unroll
    for (int it = 0; it < LN_ROWS_PB; ++it) {
        const int r = blockIdx.x + it * LN_GRID;

        // ---- Prefetch row r+LN_GRID (plain cached loads) ----
        vfloat4 w[LN_F4PT];
        if (it + 1 < LN_ROWS_PB) {
            const vfloat4* __restrict__ xn =
                reinterpret_cast<const vfloat4*>(x + (size_t)(r + LN_GRID) * LN_N);
#pragma unroll
            for (int i = 0; i < LN_F4PT; ++i)
                w[i] = xn[vbase + i * 64];
        }

        // ---- Pass 1: FP64 sum -> mean ----
        double s0 = 0.0, s1 = 0.0;
#pragma unroll
        for (int i = 0; i < LN_F4PT; ++i) {
            s0 += (double)v[i].x + (double)v[i].y;
            s1 += (double)v[i].z + (double)v[i].w;
        }
        double s = wave_allreduce_add(s0 + s1);
        if (lane == 0) red[0][wave] = s;
        __syncthreads();
        const double mean =
            ((red[0][0] + red[0][1]) + (red[0][2] + red[0][3])) * (1.0 / LN_N);

        // ---- Pass 2: FP64 sum of (x-mean)^2 -> var ----
        double q0 = 0.0, q1 = 0.0;
#pragma unroll
        for (int i = 0; i < LN_F4PT; ++i) {
            double d;
            d = (double)v[i].x - mean; q0 += d * d;
            d = (double)v[i].y - mean; q1 += d * d;
            d = (double)v[i].z - mean; q0 += d * d;
            d = (double)v[i].w - mean; q1 += d * d;
        }
        double q = wave_allreduce_add(q0 + q1);
        if (lane == 0) red[1][wave] = q;
        __syncthreads();
        const double var =
            ((red[1][0] + red[1][1]) + (red[1][2] + red[1][3])) * (1.0 / LN_N);

        // ---- NR reciprocal refinement (wave-uniform on all lanes) ----
        const double vpe = var + LN_EPS;
        double y = 1.0 / vpe;
#pragma unroll
        for (int nr = 0; nr < 5; ++nr)
            y = 0.5 * y * (3.0 - vpe * (y * y));

        // ---- Pass 3: out = fp32((x64 - mean) * y), plain cached stores ----
        vfloat4* __restrict__ orow =
            reinterpret_cast<vfloat4*>(out + (size_t)r * LN_N);
#pragma unroll
        for (int i = 0; i < LN_F4PT; ++i) {
            vfloat4 o;
            o.x = (float)(((double)v[i].x - mean) * y);
            o.y = (float)(((double)v[i].y - mean) * y);
            o.z = (float)(((double)v[i].z - mean) * y);
            o.w = (float)(((double)v[i].w - mean) * y);
            orow[vbase + i * 64] = o;
        }

        // Rotate prefetched row into place (SSA-renamed, no real moves).
        if (it + 1 < LN_ROWS_PB) {
#pragma unroll
            for (int i = 0; i < LN_F4PT; ++i) v[i] = w[i];
        }
    }
}

extern "C" void kernel_launch(void* const* d_in, const int* in_sizes, int n_in,
                              void* d_out, int out_size, void* d_ws, size_t ws_size,
                              hipStream_t stream) {
    const float* x = (const float*)d_in[0];
    float* out = (float*)d_out;
    spike_layernorm_kernel<<<LN_GRID, LN_THREADS, 0, stream>>>(x, out);
}